// Round 23
// baseline (156.040 us; speedup 1.0000x reference)
//
#include <hip/hip_runtime.h>
#include <hip/hip_bf16.h>
#include <cstdint>

#define TOPK 50
#define SUB_RANK 64        // threshold rank in the 1/8-subsampled histogram
#define HIST_STRIDE 8
#define HIST_BINS 16384
#define CAND_CAP 16384
#define NFBLK 512          // filter blocks
#define SORT_CAP 8192      // LDS bitonic capacity

typedef __attribute__((ext_vector_type(8))) short bf16x8;
typedef __attribute__((ext_vector_type(4))) float f32x4;

__device__ __forceinline__ unsigned short f2bf(float f) {
    unsigned u = __float_as_uint(f);
    u += 0x7FFFu + ((u >> 16) & 1u);   // RNE
    return (unsigned short)(u >> 16);
}

// ---------------------------------------------------------------------------
// K0: prep — 64 blocks: build Wc B-fragments, zero hist, init flags.
// No eidx pre-pass (filter offsets now atomically reserved in K1).
// ---------------------------------------------------------------------------
__global__ __launch_bounds__(256) void prep_small(const float* __restrict__ W1,
                                                  unsigned* __restrict__ Wcf4,
                                                  unsigned* __restrict__ hist,
                                                  unsigned* __restrict__ misc,
                                                  const int* __restrict__ eidx) {
    int g = blockIdx.x * blockDim.x + threadIdx.x;   // 0..16383
    {
        int l = g & 63;
        int kt = (g >> 6) & 7;
        int nt = g >> 9;                 // 0..31
        int col = nt * 16 + (l & 15);
        int kb = kt * 32 + (l >> 4) * 8;
        unsigned short h[8];
#pragma unroll
        for (int j = 0; j < 8; ++j) {
            int k = kb + j;
            float f = (col < 256) ? W1[k * 256 + col] : W1[(256 + k) * 256 + (col - 256)];
            h[j] = f2bf(f);
        }
        unsigned* dst = Wcf4 + (size_t)g * 4;
        dst[0] = (unsigned)h[0] | ((unsigned)h[1] << 16);
        dst[1] = (unsigned)h[2] | ((unsigned)h[3] << 16);
        dst[2] = (unsigned)h[4] | ((unsigned)h[5] << 16);
        dst[3] = (unsigned)h[6] | ((unsigned)h[7] << 16);
    }
    if (g < HIST_BINS) hist[g] = 0;
    if (g == 0) {
        int allz = 1;
        for (int q = 0; q < 64; ++q)
            if (eidx[2 * q + 1] != 0) { allz = 0; break; }
        misc[0] = (unsigned)allz;  // 1 => int64 layout
        misc[3] = 0;               // candidate counter
        misc[4] = 0;               // valid-edge counter (atomic reservation)
    }
}

// ---------------------------------------------------------------------------
// K1: HETEROGENEOUS — blocks [0,NG): verified fused cvt+GEMM (62us body);
// blocks [NG,NG+NFBLK): filter body — count own chunk, atomically reserve
// space in misc[4], write compacted triples (order non-deterministic across
// blocks, but output is invariant: topk sorts a strict total order).
// ---------------------------------------------------------------------------
__global__ __launch_bounds__(256) void gemm_plus_write(const float* __restrict__ emb,
                                                       const bf16x8* __restrict__ Bv,
                                                       const float* __restrict__ b1,
                                                       unsigned char* __restrict__ C8,
                                                       int M, int NG,
                                                       const int* __restrict__ eidx,
                                                       unsigned* __restrict__ misc,
                                                       int* __restrict__ vsrc,
                                                       int* __restrict__ vdst,
                                                       int* __restrict__ vid, int E) {
    __shared__ uint4 afrag[2048];
    const int t = threadIdx.x;

    if ((int)blockIdx.x < NG) {
        // ---------------- GEMM body (byte-identical to round-22) ----------
        const int w = t >> 6;
        const int l = t & 63;

        uint2* w2 = (uint2*)afrag;
#pragma unroll
        for (int iter = 0; iter < 16; ++iter) {
            int r = iter * 4 + w;
            int c0 = l * 4;
            int gr = blockIdx.x * 64 + r;
            float4 v = make_float4(0.f, 0.f, 0.f, 0.f);
            if (gr < M) v = *(const float4*)&emb[(size_t)gr * 256 + c0];
            unsigned u0 = (unsigned)f2bf(v.x) | ((unsigned)f2bf(v.y) << 16);
            unsigned u1 = (unsigned)f2bf(v.z) | ((unsigned)f2bf(v.w) << 16);
            int mt = r >> 4;
            int kt = c0 >> 5;
            int lane = (r & 15) + ((c0 & 31) >> 3) * 16;
            int f = mt * 8 + kt;
            int slot = f * 64 + (lane ^ (f & 7));
            w2[slot * 2 + ((c0 & 7) >> 2)] = make_uint2(u0, u1);
        }
        __syncthreads();

        const int wn = w;
#pragma unroll
        for (int nh = 0; nh < 2; ++nh) {
            f32x4 acc[4][4];
#pragma unroll
            for (int i = 0; i < 4; ++i)
#pragma unroll
                for (int j = 0; j < 4; ++j) acc[i][j] = (f32x4){0.f, 0.f, 0.f, 0.f};

            const int nt0 = wn * 8 + nh * 4;
            bf16x8 bcur[4];
#pragma unroll
            for (int j = 0; j < 4; ++j)
                bcur[j] = Bv[(size_t)((nt0 + j) * 8 + 0) * 64 + l];

#pragma unroll
            for (int kt = 0; kt < 8; ++kt) {
                bf16x8 af[4];
#pragma unroll
                for (int i = 0; i < 4; ++i)
                    af[i] = *(const bf16x8*)&afrag[(i * 8 + kt) * 64 + (l ^ kt)];
                bf16x8 bnxt[4];
                if (kt < 7) {
#pragma unroll
                    for (int j = 0; j < 4; ++j)
                        bnxt[j] = Bv[(size_t)((nt0 + j) * 8 + kt + 1) * 64 + l];
                }
#pragma unroll
                for (int i = 0; i < 4; ++i)
#pragma unroll
                    for (int j = 0; j < 4; ++j)
                        acc[i][j] = __builtin_amdgcn_mfma_f32_16x16x32_bf16(af[i], bcur[j], acc[i][j], 0, 0, 0);
                if (kt < 7) {
#pragma unroll
                    for (int j = 0; j < 4; ++j) bcur[j] = bnxt[j];
                }
            }

#pragma unroll
            for (int i = 0; i < 4; ++i) {
                int row0 = blockIdx.x * 64 + i * 16 + (l >> 4) * 4;
#pragma unroll
                for (int j = 0; j < 4; ++j) {
                    int col = (nt0 + j) * 16 + (l & 15);
                    float bias = (col < 256) ? b1[col] : 0.f;
#pragma unroll
                    for (int r = 0; r < 4; ++r) {
                        float v = acc[i][j][r] + bias;
                        int pk = __builtin_amdgcn_cvt_pk_fp8_f32(v, v, 0, false);
                        C8[(size_t)(row0 + r) * 512 + col] = (unsigned char)(pk & 0xFF);
                    }
                }
            }
        }
    } else {
        // ------------- filter body: count -> atomic reserve -> write ------
        const int is64 = (int)misc[0];
        const int bid = (int)blockIdx.x - NG;          // 0..NFBLK-1
        unsigned* red = (unsigned*)afrag;              // [256]
        unsigned* wcnt = red + 256;                    // [4]
        unsigned* sbase = wcnt + 4;                    // [1]

        const int chunk = (E + NFBLK - 1) / NFBLK;
        const int lo = bid * chunk;
        const int hi = min(E, lo + chunk);
        const int lane = t & 63;
        const int w = t >> 6;

        // pass 1: count this chunk's valid edges
        unsigned cnt = 0;
        for (int e = lo + t; e < hi; e += blockDim.x) {
            int s, d;
            if (is64) {
                s = ((const int2*)eidx)[e].x;
                d = ((const int2*)eidx)[(size_t)e + E].x;
            } else {
                s = eidx[e];
                d = eidx[e + E];
            }
            cnt += (s < d);
        }
#pragma unroll
        for (int off = 32; off; off >>= 1) cnt += __shfl_xor(cnt, off, 64);
        if (lane == 0) wcnt[w] = cnt;
        __syncthreads();
        if (t == 0)
            sbase[0] = atomicAdd(&misc[4], wcnt[0] + wcnt[1] + wcnt[2] + wcnt[3]);
        __syncthreads();
        unsigned running = sbase[0];
        __syncthreads();

        // pass 2: write at reserved base (L2-warm re-read)
        for (int base = lo; base < hi; base += blockDim.x) {
            int e = base + t;
            bool valid = false;
            int s = 0, d = 0;
            if (e < hi) {
                if (is64) {
                    s = ((const int2*)eidx)[e].x;
                    d = ((const int2*)eidx)[(size_t)e + E].x;
                } else {
                    s = eidx[e];
                    d = eidx[e + E];
                }
                valid = s < d;
            }
            unsigned long long m = __ballot(valid);
            unsigned pfx = __popcll(m & ((1ull << lane) - 1ull));
            if (lane == 0) wcnt[w] = __popcll(m);
            __syncthreads();
            unsigned wbase = running;
            for (int i = 0; i < w; ++i) wbase += wcnt[i];
            if (valid) {
                unsigned p = wbase + pfx;
                vsrc[p] = s;
                vdst[p] = d;
                vid[p] = e;
            }
            unsigned tot = wcnt[0] + wcnt[1] + wcnt[2] + wcnt[3];
            __syncthreads();
            running += tot;
        }
    }
}

// ---------------------------------------------------------------------------
// K2: fp8 edge scoring on compacted list. 16 lanes/edge, 4 edges/wave.
// ---------------------------------------------------------------------------
__device__ __forceinline__ float dotq(unsigned a, unsigned b, float4 w) {
    float s;
    s  = fmaxf(__builtin_amdgcn_cvt_f32_fp8(a, 0) + __builtin_amdgcn_cvt_f32_fp8(b, 0), 0.f) * w.x;
    s += fmaxf(__builtin_amdgcn_cvt_f32_fp8(a, 1) + __builtin_amdgcn_cvt_f32_fp8(b, 1), 0.f) * w.y;
    s += fmaxf(__builtin_amdgcn_cvt_f32_fp8(a, 2) + __builtin_amdgcn_cvt_f32_fp8(b, 2), 0.f) * w.z;
    s += fmaxf(__builtin_amdgcn_cvt_f32_fp8(a, 3) + __builtin_amdgcn_cvt_f32_fp8(b, 3), 0.f) * w.w;
    return s;
}

__global__ __launch_bounds__(256) void edge_score_fp8(const unsigned char* __restrict__ C8,
                                                      const int* __restrict__ vsrc,
                                                      const int* __restrict__ vdst,
                                                      const float* __restrict__ W2,
                                                      const float* __restrict__ b2,
                                                      float* __restrict__ svals,
                                                      const unsigned* __restrict__ misc) {
    const int V = (int)misc[4];
    const int lane = threadIdx.x & 63;
    const int q = lane & 15;
    const int g = lane >> 4;
    const int wid = blockIdx.x * (blockDim.x >> 6) + (threadIdx.x >> 6);
    const int nw = gridDim.x * (blockDim.x >> 6);

    const float4 w0 = *(const float4*)&W2[q * 16 + 0];
    const float4 w1 = *(const float4*)&W2[q * 16 + 4];
    const float4 w2 = *(const float4*)&W2[q * 16 + 8];
    const float4 w3 = *(const float4*)&W2[q * 16 + 12];
    const float bb2 = b2[0];

    for (int base = wid * 4; base < V; base += nw * 4) {
        const int slot = base + g;
        const bool ok = slot < V;
        const int src = ok ? vsrc[slot] : 0;
        const int dst = ok ? vdst[slot] : 0;
        const uint4 ua = *(const uint4*)(C8 + (size_t)src * 512 + q * 16);
        const uint4 ub = *(const uint4*)(C8 + (size_t)dst * 512 + 256 + q * 16);
        float p = dotq(ua.x, ub.x, w0);
        p += dotq(ua.y, ub.y, w1);
        p += dotq(ua.z, ub.z, w2);
        p += dotq(ua.w, ub.w, w3);
        p += __shfl_xor(p, 1, 64);
        p += __shfl_xor(p, 2, 64);
        p += __shfl_xor(p, 4, 64);
        p += __shfl_xor(p, 8, 64);
        if (q == 0 && ok) {
            float z = p + bb2;
            float sc = 1.0f / (1.0f + expf(-z));
            svals[slot] = sc;
        }
    }
}

// ---------------------------------------------------------------------------
// K3: SUBSAMPLED histogram — every HIST_STRIDE-th score (1/8 sample).
// ---------------------------------------------------------------------------
__global__ __launch_bounds__(256) void hist_kernel(const float* __restrict__ svals,
                                                   const unsigned* __restrict__ misc,
                                                   unsigned* __restrict__ hist) {
    __shared__ unsigned lh[HIST_BINS];
    const int V = (int)misc[4] / HIST_STRIDE;
    const int t = threadIdx.x;
    for (int i = t; i < HIST_BINS; i += 256) lh[i] = 0;
    __syncthreads();
    int i = blockIdx.x * blockDim.x + t;
    int stride = gridDim.x * blockDim.x;
    for (int v = i; v < V; v += stride)
        atomicAdd(&lh[__float_as_uint(svals[(size_t)v * HIST_STRIDE]) >> 16], 1u);
    __syncthreads();
    for (int b = t; b < HIST_BINS; b += 256) {
        unsigned c = lh[b];
        if (c) atomicAdd(&hist[b], c);
    }
}

// ---------------------------------------------------------------------------
// K4: compact with fused threshold scan (rank SUB_RANK in subsampled hist).
// ---------------------------------------------------------------------------
__global__ __launch_bounds__(256) void compact(const float* __restrict__ svals,
                                               const int* __restrict__ vid,
                                               const unsigned* __restrict__ hist,
                                               unsigned* __restrict__ misc,
                                               unsigned long long* __restrict__ cand) {
    __shared__ unsigned chunk[256];
    __shared__ unsigned s_thr;
    const int t = threadIdx.x;
    {
        unsigned s = 0;
        for (int i = 0; i < 64; ++i) s += hist[t * 64 + i];
        chunk[t] = s;
    }
    __syncthreads();
    if (t == 0) {
        unsigned cum = 0;
        int c;
        unsigned thr = 0;
        for (c = 255; c >= 0; --c) {
            if (cum + chunk[c] >= SUB_RANK) break;
            cum += chunk[c];
        }
        if (c >= 0) {
            for (int b = c * 64 + 63; b >= c * 64; --b) {
                cum += hist[b];
                if (cum >= SUB_RANK) { thr = ((unsigned)b) << 16; break; }
            }
        }
        s_thr = thr;
    }
    __syncthreads();
    const unsigned thr = s_thr;

    const int V = (int)misc[4];
    int i = blockIdx.x * blockDim.x + t;
    int stride = gridDim.x * blockDim.x;
    for (int v = i; v < V; v += stride) {
        unsigned bits = __float_as_uint(svals[v]);
        if (bits >= thr) {
            unsigned pos = atomicAdd(&misc[3], 1u);
            if (pos < CAND_CAP)
                cand[pos] = ((unsigned long long)bits << 32) |
                            (unsigned)(0xFFFFFFFFu - (unsigned)vid[v]);
        }
    }
}

// ---------------------------------------------------------------------------
// K5: exact fp32 rescore of candidates from emb/W1/b1/W2/b2.
// ---------------------------------------------------------------------------
__global__ __launch_bounds__(256) void rescore(const float* __restrict__ emb,
                                               const float* __restrict__ W1,
                                               const float* __restrict__ b1,
                                               const float* __restrict__ W2,
                                               const float* __restrict__ b2,
                                               const int* __restrict__ eidx,
                                               const unsigned long long* __restrict__ cand,
                                               const unsigned* __restrict__ misc,
                                               unsigned long long* __restrict__ rescored,
                                               int E) {
    __shared__ float es[256], ed[256];
    __shared__ float red[256];
    const int C = (int)min(misc[3], (unsigned)CAND_CAP);
    const int is64 = (int)misc[0];
    const int t = threadIdx.x;
    for (int c = blockIdx.x; c < C; c += gridDim.x) {
        unsigned long long entry = cand[c];
        unsigned e = 0xFFFFFFFFu - (unsigned)(entry & 0xFFFFFFFFu);
        int src, dst;
        if (is64) {
            src = eidx[2 * (size_t)e];
            dst = eidx[2 * ((size_t)e + E)];
        } else {
            src = eidx[e];
            dst = eidx[e + E];
        }
        es[t] = emb[(size_t)src * 256 + t];
        ed[t] = emb[(size_t)dst * 256 + t];
        __syncthreads();
        float h = b1[t];
#pragma unroll 8
        for (int k = 0; k < 256; ++k) h += es[k] * W1[k * 256 + t];
#pragma unroll 8
        for (int k = 0; k < 256; ++k) h += ed[k] * W1[(256 + k) * 256 + t];
        red[t] = fmaxf(h, 0.f) * W2[t];
        __syncthreads();
        for (int s = 128; s; s >>= 1) {
            if (t < s) red[t] += red[t + s];
            __syncthreads();
        }
        if (t == 0) {
            float z = red[0] + b2[0];
            float sc = 1.0f / (1.0f + expf(-z));
            rescored[c] = ((unsigned long long)__float_as_uint(sc) << 32) |
                          (unsigned)(0xFFFFFFFFu - e);
        }
        __syncthreads();
    }
}

// ---------------------------------------------------------------------------
// K6: top-K via single-block LDS bitonic sort (descending), parallel decode.
// ---------------------------------------------------------------------------
__global__ __launch_bounds__(256) void final_topk(unsigned long long* __restrict__ rescored,
                                                  const unsigned* __restrict__ misc,
                                                  const int* __restrict__ eidx,
                                                  float* __restrict__ out, int E) {
    __shared__ unsigned long long a[SORT_CAP];
    const int t = threadIdx.x;
    const int C = (int)min(misc[3], (unsigned)CAND_CAP);
    const int is64 = (int)misc[0];

    if (C <= SORT_CAP) {
        int n = 256;
        while (n < C) n <<= 1;
        for (int i = t; i < n; i += 256) a[i] = (i < C) ? rescored[i] : 0ull;
        __syncthreads();
        for (int k = 2; k <= n; k <<= 1) {
            for (int j = k >> 1; j > 0; j >>= 1) {
                for (int i = t; i < n; i += 256) {
                    int ixj = i ^ j;
                    if (ixj > i) {
                        unsigned long long x = a[i], y = a[ixj];
                        bool sw = ((i & k) == 0) ? (x < y) : (x > y);
                        if (sw) { a[i] = y; a[ixj] = x; }
                    }
                }
                __syncthreads();
            }
        }
        if (t < TOPK) {
            unsigned long long m = a[t];
            if (m != 0ull) {
                unsigned bits = (unsigned)(m >> 32);
                unsigned e = 0xFFFFFFFFu - (unsigned)(m & 0xFFFFFFFFu);
                int src, dst;
                if (is64) {
                    src = eidx[2 * (size_t)e];
                    dst = eidx[2 * ((size_t)e + E)];
                } else {
                    src = eidx[e];
                    dst = eidx[e + E];
                }
                out[t] = (float)src;
                out[TOPK + t] = (float)dst;
                out[2 * TOPK + t] = __uint_as_float(bits);
            } else {
                out[t] = -1.f;
                out[TOPK + t] = -1.f;
                out[2 * TOPK + t] = -1.f;
            }
        }
        return;
    }

    // fallback: serial removal tournament (pathological only)
    __shared__ unsigned long long red[256];
    for (int r = 0; r < TOPK; ++r) {
        unsigned long long best = 0ull;
        for (int i = t; i < C; i += 256) {
            unsigned long long v = rescored[i];
            if (v > best) best = v;
        }
        red[t] = best;
        __syncthreads();
        for (int s = 128; s; s >>= 1) {
            if (t < s) {
                if (red[t + s] > red[t]) red[t] = red[t + s];
            }
            __syncthreads();
        }
        unsigned long long m = red[0];
        __syncthreads();
        for (int i = t; i < C; i += 256)
            if (rescored[i] == m) rescored[i] = 0ull;
        if (t == 0) {
            if (m != 0ull) {
                unsigned bits = (unsigned)(m >> 32);
                unsigned e = 0xFFFFFFFFu - (unsigned)(m & 0xFFFFFFFFu);
                int src, dst;
                if (is64) {
                    src = eidx[2 * (size_t)e];
                    dst = eidx[2 * ((size_t)e + E)];
                } else {
                    src = eidx[e];
                    dst = eidx[e + E];
                }
                out[r] = (float)src;
                out[TOPK + r] = (float)dst;
                out[2 * TOPK + r] = __uint_as_float(bits);
            } else {
                out[r] = -1.f;
                out[TOPK + r] = -1.f;
                out[2 * TOPK + r] = -1.f;
            }
        }
        __syncthreads();
    }
}

// ---------------------------------------------------------------------------
extern "C" void kernel_launch(void* const* d_in, const int* in_sizes, int n_in,
                              void* d_out, int out_size, void* d_ws, size_t ws_size,
                              hipStream_t stream) {
    const float* emb = (const float*)d_in[0];
    const float* W1  = (const float*)d_in[1];
    const float* b1  = (const float*)d_in[2];
    const float* W2  = (const float*)d_in[3];
    const float* b2  = (const float*)d_in[4];
    const int*   eidx = (const int*)d_in[5];

    const int M = in_sizes[0] / 256;           // 50000
    const int E = in_sizes[5] / 2;             // 800000
    const int Mpad = ((M + 63) / 64) * 64;     // 50048
    const int NG = Mpad / 64;                  // gemm blocks (782)

    char* p = (char*)d_ws;
    auto alloc = [&](size_t bytes) {
        char* r = p;
        p += (bytes + 255) & ~(size_t)255;
        return r;
    };
    unsigned* Wcf4 = (unsigned*)alloc(256 * 512 * 2);              // bf16 B-frags
    unsigned char* C8 = (unsigned char*)alloc((size_t)Mpad * 512); // fp8 C
    float* svals = (float*)alloc((size_t)E * 4);
    int* vsrc = (int*)alloc((size_t)E * 4);
    int* vdst = (int*)alloc((size_t)E * 4);
    int* vid  = (int*)alloc((size_t)E * 4);
    unsigned* hist = (unsigned*)alloc(HIST_BINS * 4);
    unsigned long long* cand = (unsigned long long*)alloc(CAND_CAP * 8);
    unsigned long long* resc = (unsigned long long*)alloc(CAND_CAP * 8);
    unsigned* misc = (unsigned*)alloc(256);

    float* out = (float*)d_out;

    prep_small<<<64, 256, 0, stream>>>(W1, Wcf4, hist, misc, eidx);

    gemm_plus_write<<<NG + NFBLK, 256, 0, stream>>>(emb, (const bf16x8*)Wcf4, b1, C8,
                                                    M, NG, eidx, misc,
                                                    vsrc, vdst, vid, E);

    edge_score_fp8<<<2048, 256, 0, stream>>>(C8, vsrc, vdst, W2, b2, svals, misc);

    hist_kernel<<<128, 256, 0, stream>>>(svals, misc, hist);

    compact<<<512, 256, 0, stream>>>(svals, vid, hist, misc, cand);

    rescore<<<1024, 256, 0, stream>>>(emb, W1, b1, W2, b2, eidx, cand, misc, resc, E);

    final_topk<<<1, 256, 0, stream>>>(resc, misc, eidx, out, E);
}

// Round 25
// 142.004 us; speedup vs baseline: 1.0988x; 1.0988x over previous
//
#include <hip/hip_runtime.h>
#include <hip/hip_bf16.h>
#include <cstdint>

#define TOPK 50
#define SUB_RANK 64        // threshold rank in the 1/8-subsampled histogram
#define HIST_STRIDE 8
#define HIST_BINS 16384
#define CAND_CAP 16384
#define NFBLK 512          // filter blocks
#define SORT_CAP 8192      // LDS bitonic capacity

typedef __attribute__((ext_vector_type(8))) short bf16x8;
typedef __attribute__((ext_vector_type(4))) float f32x4;

__device__ __forceinline__ unsigned short f2bf(float f) {
    unsigned u = __float_as_uint(f);
    u += 0x7FFFu + ((u >> 16) & 1u);   // RNE
    return (unsigned short)(u >> 16);
}

// ---------------------------------------------------------------------------
// K0: prep+count — blocks 0..63 build Wc B-fragments and zero hist; ALL 512
// blocks count valid edges in their chunk. is64 recomputed per-block.
// ---------------------------------------------------------------------------
__global__ __launch_bounds__(256) void prep_count(const float* __restrict__ W1,
                                                  unsigned* __restrict__ Wcf4,
                                                  unsigned* __restrict__ hist,
                                                  unsigned* __restrict__ misc,
                                                  const int* __restrict__ eidx,
                                                  unsigned* __restrict__ bcount, int E) {
    __shared__ int s_is64;
    if (threadIdx.x == 0) {
        int allz = 1;
        for (int q = 0; q < 64; ++q)
            if (eidx[2 * q + 1] != 0) { allz = 0; break; }
        s_is64 = allz;
    }
    __syncthreads();
    const int is64 = s_is64;

    int g = blockIdx.x * blockDim.x + threadIdx.x;
    if (g < 256 * 64) {
        int l = g & 63;
        int kt = (g >> 6) & 7;
        int nt = g >> 9;
        int col = nt * 16 + (l & 15);
        int kb = kt * 32 + (l >> 4) * 8;
        unsigned short h[8];
#pragma unroll
        for (int j = 0; j < 8; ++j) {
            int k = kb + j;
            float f = (col < 256) ? W1[k * 256 + col] : W1[(256 + k) * 256 + (col - 256)];
            h[j] = f2bf(f);
        }
        unsigned* dst = Wcf4 + (size_t)g * 4;
        dst[0] = (unsigned)h[0] | ((unsigned)h[1] << 16);
        dst[1] = (unsigned)h[2] | ((unsigned)h[3] << 16);
        dst[2] = (unsigned)h[4] | ((unsigned)h[5] << 16);
        dst[3] = (unsigned)h[6] | ((unsigned)h[7] << 16);
    }
    if (g < HIST_BINS) hist[g] = 0;
    if (g == 0) {
        misc[0] = (unsigned)is64;
        misc[2] = 0;
        misc[3] = 0;   // candidate counter
        misc[4] = 0;   // valid-edge counter
    }

    const int chunk = (E + gridDim.x - 1) / gridDim.x;
    const int lo = blockIdx.x * chunk;
    const int hi = min(E, lo + chunk);
    unsigned cnt = 0;
    for (int e = lo + threadIdx.x; e < hi; e += blockDim.x) {
        int s, d;
        if (is64) {
            s = ((const int2*)eidx)[e].x;
            d = ((const int2*)eidx)[(size_t)e + E].x;
        } else {
            s = eidx[e];
            d = eidx[e + E];
        }
        cnt += (s < d);
    }
#pragma unroll
    for (int off = 32; off; off >>= 1) cnt += __shfl_xor(cnt, off, 64);
    __shared__ unsigned wsum[4];
    if ((threadIdx.x & 63) == 0) wsum[threadIdx.x >> 6] = cnt;
    __syncthreads();
    if (threadIdx.x == 0)
        bcount[blockIdx.x] = wsum[0] + wsum[1] + wsum[2] + wsum[3];
}

// ---------------------------------------------------------------------------
// K1: HETEROGENEOUS — blocks [0,NG): verified fused cvt+GEMM (62us body);
// blocks [NG,NG+NFBLK): verified write_valid_scan body (independent data,
// hides under the GEMM's idle machine). LDS is a union (32 KB).
// ---------------------------------------------------------------------------
__global__ __launch_bounds__(256) void gemm_plus_write(const float* __restrict__ emb,
                                                       const bf16x8* __restrict__ Bv,
                                                       const float* __restrict__ b1,
                                                       unsigned char* __restrict__ C8,
                                                       int M, int NG,
                                                       const int* __restrict__ eidx,
                                                       unsigned* __restrict__ misc,
                                                       const unsigned* __restrict__ bcount,
                                                       int* __restrict__ vsrc,
                                                       int* __restrict__ vdst,
                                                       int* __restrict__ vid, int E) {
    __shared__ uint4 afrag[2048];
    const int t = threadIdx.x;

    if ((int)blockIdx.x < NG) {
        // ---------------- GEMM body (byte-identical to round-22) ----------
        const int w = t >> 6;
        const int l = t & 63;

        uint2* w2 = (uint2*)afrag;
#pragma unroll
        for (int iter = 0; iter < 16; ++iter) {
            int r = iter * 4 + w;
            int c0 = l * 4;
            int gr = blockIdx.x * 64 + r;
            float4 v = make_float4(0.f, 0.f, 0.f, 0.f);
            if (gr < M) v = *(const float4*)&emb[(size_t)gr * 256 + c0];
            unsigned u0 = (unsigned)f2bf(v.x) | ((unsigned)f2bf(v.y) << 16);
            unsigned u1 = (unsigned)f2bf(v.z) | ((unsigned)f2bf(v.w) << 16);
            int mt = r >> 4;
            int kt = c0 >> 5;
            int lane = (r & 15) + ((c0 & 31) >> 3) * 16;
            int f = mt * 8 + kt;
            int slot = f * 64 + (lane ^ (f & 7));
            w2[slot * 2 + ((c0 & 7) >> 2)] = make_uint2(u0, u1);
        }
        __syncthreads();

        const int wn = w;
#pragma unroll
        for (int nh = 0; nh < 2; ++nh) {
            f32x4 acc[4][4];
#pragma unroll
            for (int i = 0; i < 4; ++i)
#pragma unroll
                for (int j = 0; j < 4; ++j) acc[i][j] = (f32x4){0.f, 0.f, 0.f, 0.f};

            const int nt0 = wn * 8 + nh * 4;
            bf16x8 bcur[4];
#pragma unroll
            for (int j = 0; j < 4; ++j)
                bcur[j] = Bv[(size_t)((nt0 + j) * 8 + 0) * 64 + l];

#pragma unroll
            for (int kt = 0; kt < 8; ++kt) {
                bf16x8 af[4];
#pragma unroll
                for (int i = 0; i < 4; ++i)
                    af[i] = *(const bf16x8*)&afrag[(i * 8 + kt) * 64 + (l ^ kt)];
                bf16x8 bnxt[4];
                if (kt < 7) {
#pragma unroll
                    for (int j = 0; j < 4; ++j)
                        bnxt[j] = Bv[(size_t)((nt0 + j) * 8 + kt + 1) * 64 + l];
                }
#pragma unroll
                for (int i = 0; i < 4; ++i)
#pragma unroll
                    for (int j = 0; j < 4; ++j)
                        acc[i][j] = __builtin_amdgcn_mfma_f32_16x16x32_bf16(af[i], bcur[j], acc[i][j], 0, 0, 0);
                if (kt < 7) {
#pragma unroll
                    for (int j = 0; j < 4; ++j) bcur[j] = bnxt[j];
                }
            }

#pragma unroll
            for (int i = 0; i < 4; ++i) {
                int row0 = blockIdx.x * 64 + i * 16 + (l >> 4) * 4;
#pragma unroll
                for (int j = 0; j < 4; ++j) {
                    int col = (nt0 + j) * 16 + (l & 15);
                    float bias = (col < 256) ? b1[col] : 0.f;
#pragma unroll
                    for (int r = 0; r < 4; ++r) {
                        float v = acc[i][j][r] + bias;
                        int pk = __builtin_amdgcn_cvt_pk_fp8_f32(v, v, 0, false);
                        C8[(size_t)(row0 + r) * 512 + col] = (unsigned char)(pk & 0xFF);
                    }
                }
            }
        }
    } else {
        // ------------- write_valid_scan body (byte-identical logic) -------
        const int is64 = (int)misc[0];
        const int bid = (int)blockIdx.x - NG;          // 0..NFBLK-1
        unsigned* red = (unsigned*)afrag;              // [256]
        unsigned* wcnt = red + 256;                    // [4]

        unsigned c0 = bcount[t], c1 = bcount[t + 256];
        unsigned pa = ((t < bid) ? c0 : 0u) + ((t + 256 < bid) ? c1 : 0u);
        red[t] = pa;
        __syncthreads();
        for (int s = 128; s; s >>= 1) {
            if (t < s) red[t] += red[t + s];
            __syncthreads();
        }
        const unsigned myoff = red[0];
        __syncthreads();
        red[t] = c0 + c1;
        __syncthreads();
        for (int s = 128; s; s >>= 1) {
            if (t < s) red[t] += red[t + s];
            __syncthreads();
        }
        if (bid == 0 && t == 0) misc[4] = red[0];

        const int chunk = (E + NFBLK - 1) / NFBLK;
        const int lo = bid * chunk;
        const int hi = min(E, lo + chunk);
        const int lane = t & 63;
        const int w = t >> 6;
        unsigned running = myoff;
        for (int base = lo; base < hi; base += blockDim.x) {
            int e = base + t;
            bool valid = false;
            int s = 0, d = 0;
            if (e < hi) {
                if (is64) {
                    s = ((const int2*)eidx)[e].x;
                    d = ((const int2*)eidx)[(size_t)e + E].x;
                } else {
                    s = eidx[e];
                    d = eidx[e + E];
                }
                valid = s < d;
            }
            unsigned long long m = __ballot(valid);
            unsigned pfx = __popcll(m & ((1ull << lane) - 1ull));
            if (lane == 0) wcnt[w] = __popcll(m);
            __syncthreads();
            unsigned wbase = running;
            for (int i = 0; i < w; ++i) wbase += wcnt[i];
            if (valid) {
                unsigned p = wbase + pfx;
                vsrc[p] = s;
                vdst[p] = d;
                vid[p] = e;
            }
            unsigned tot = wcnt[0] + wcnt[1] + wcnt[2] + wcnt[3];
            __syncthreads();
            running += tot;
        }
    }
}

// ---------------------------------------------------------------------------
// K2: fp8 edge scoring — 8 lanes/edge, 8 edges/wave (doubled MLP: 4
// independent 16B loads/lane, 3-shuffle reduce). No atomics, no LDS.
// ---------------------------------------------------------------------------
__device__ __forceinline__ float dotq(unsigned a, unsigned b, float4 w) {
    float s;
    s  = fmaxf(__builtin_amdgcn_cvt_f32_fp8(a, 0) + __builtin_amdgcn_cvt_f32_fp8(b, 0), 0.f) * w.x;
    s += fmaxf(__builtin_amdgcn_cvt_f32_fp8(a, 1) + __builtin_amdgcn_cvt_f32_fp8(b, 1), 0.f) * w.y;
    s += fmaxf(__builtin_amdgcn_cvt_f32_fp8(a, 2) + __builtin_amdgcn_cvt_f32_fp8(b, 2), 0.f) * w.z;
    s += fmaxf(__builtin_amdgcn_cvt_f32_fp8(a, 3) + __builtin_amdgcn_cvt_f32_fp8(b, 3), 0.f) * w.w;
    return s;
}

__global__ __launch_bounds__(256) void edge_score_fp8(const unsigned char* __restrict__ C8,
                                                      const int* __restrict__ vsrc,
                                                      const int* __restrict__ vdst,
                                                      const float* __restrict__ W2,
                                                      const float* __restrict__ b2,
                                                      float* __restrict__ svals,
                                                      const unsigned* __restrict__ misc) {
    const int V = (int)misc[4];
    const int lane = threadIdx.x & 63;
    const int q = lane & 7;    // element group (32 elems)
    const int g = lane >> 3;   // edge slot within wave (0..7)
    const int wid = blockIdx.x * (blockDim.x >> 6) + (threadIdx.x >> 6);
    const int nw = gridDim.x * (blockDim.x >> 6);

    float4 wr[8];
#pragma unroll
    for (int j = 0; j < 8; ++j) wr[j] = *(const float4*)&W2[q * 32 + j * 4];
    const float bb2 = b2[0];

    for (int base = wid * 8; base < V; base += nw * 8) {
        const int slot = base + g;
        const bool ok = slot < V;
        const int src = ok ? vsrc[slot] : 0;
        const int dst = ok ? vdst[slot] : 0;
        const unsigned char* ps = C8 + (size_t)src * 512 + q * 32;
        const unsigned char* pd = C8 + (size_t)dst * 512 + 256 + q * 32;
        const uint4 ua0 = *(const uint4*)(ps);
        const uint4 ua1 = *(const uint4*)(ps + 16);
        const uint4 ub0 = *(const uint4*)(pd);
        const uint4 ub1 = *(const uint4*)(pd + 16);
        float p = dotq(ua0.x, ub0.x, wr[0]);
        p += dotq(ua0.y, ub0.y, wr[1]);
        p += dotq(ua0.z, ub0.z, wr[2]);
        p += dotq(ua0.w, ub0.w, wr[3]);
        p += dotq(ua1.x, ub1.x, wr[4]);
        p += dotq(ua1.y, ub1.y, wr[5]);
        p += dotq(ua1.z, ub1.z, wr[6]);
        p += dotq(ua1.w, ub1.w, wr[7]);
        p += __shfl_xor(p, 1, 64);
        p += __shfl_xor(p, 2, 64);
        p += __shfl_xor(p, 4, 64);
        if (q == 0 && ok) {
            float z = p + bb2;
            float sc = 1.0f / (1.0f + expf(-z));
            svals[slot] = sc;
        }
    }
}

// ---------------------------------------------------------------------------
// K3: SUBSAMPLED histogram — every HIST_STRIDE-th score (1/8 sample).
// ---------------------------------------------------------------------------
__global__ __launch_bounds__(256) void hist_kernel(const float* __restrict__ svals,
                                                   const unsigned* __restrict__ misc,
                                                   unsigned* __restrict__ hist) {
    __shared__ unsigned lh[HIST_BINS];
    const int V = (int)misc[4] / HIST_STRIDE;
    const int t = threadIdx.x;
    for (int i = t; i < HIST_BINS; i += 256) lh[i] = 0;
    __syncthreads();
    int i = blockIdx.x * blockDim.x + t;
    int stride = gridDim.x * blockDim.x;
    for (int v = i; v < V; v += stride)
        atomicAdd(&lh[__float_as_uint(svals[(size_t)v * HIST_STRIDE]) >> 16], 1u);
    __syncthreads();
    for (int b = t; b < HIST_BINS; b += 256) {
        unsigned c = lh[b];
        if (c) atomicAdd(&hist[b], c);
    }
}

// ---------------------------------------------------------------------------
// K4: compact with fused threshold scan (rank SUB_RANK in subsampled hist).
// ---------------------------------------------------------------------------
__global__ __launch_bounds__(256) void compact(const float* __restrict__ svals,
                                               const int* __restrict__ vid,
                                               const unsigned* __restrict__ hist,
                                               unsigned* __restrict__ misc,
                                               unsigned long long* __restrict__ cand) {
    __shared__ unsigned chunk[256];
    __shared__ unsigned s_thr;
    const int t = threadIdx.x;
    {
        unsigned s = 0;
        for (int i = 0; i < 64; ++i) s += hist[t * 64 + i];
        chunk[t] = s;
    }
    __syncthreads();
    if (t == 0) {
        unsigned cum = 0;
        int c;
        unsigned thr = 0;
        for (c = 255; c >= 0; --c) {
            if (cum + chunk[c] >= SUB_RANK) break;
            cum += chunk[c];
        }
        if (c >= 0) {
            for (int b = c * 64 + 63; b >= c * 64; --b) {
                cum += hist[b];
                if (cum >= SUB_RANK) { thr = ((unsigned)b) << 16; break; }
            }
        }
        s_thr = thr;
    }
    __syncthreads();
    const unsigned thr = s_thr;

    const int V = (int)misc[4];
    int i = blockIdx.x * blockDim.x + t;
    int stride = gridDim.x * blockDim.x;
    for (int v = i; v < V; v += stride) {
        unsigned bits = __float_as_uint(svals[v]);
        if (bits >= thr) {
            unsigned pos = atomicAdd(&misc[3], 1u);
            if (pos < CAND_CAP)
                cand[pos] = ((unsigned long long)bits << 32) |
                            (unsigned)(0xFFFFFFFFu - (unsigned)vid[v]);
        }
    }
}

// ---------------------------------------------------------------------------
// K5: exact fp32 rescore of candidates from emb/W1/b1/W2/b2.
// ---------------------------------------------------------------------------
__global__ __launch_bounds__(256) void rescore(const float* __restrict__ emb,
                                               const float* __restrict__ W1,
                                               const float* __restrict__ b1,
                                               const float* __restrict__ W2,
                                               const float* __restrict__ b2,
                                               const int* __restrict__ eidx,
                                               const unsigned long long* __restrict__ cand,
                                               const unsigned* __restrict__ misc,
                                               unsigned long long* __restrict__ rescored,
                                               int E) {
    __shared__ float es[256], ed[256];
    __shared__ float red[256];
    const int C = (int)min(misc[3], (unsigned)CAND_CAP);
    const int is64 = (int)misc[0];
    const int t = threadIdx.x;
    for (int c = blockIdx.x; c < C; c += gridDim.x) {
        unsigned long long entry = cand[c];
        unsigned e = 0xFFFFFFFFu - (unsigned)(entry & 0xFFFFFFFFu);
        int src, dst;
        if (is64) {
            src = eidx[2 * (size_t)e];
            dst = eidx[2 * ((size_t)e + E)];
        } else {
            src = eidx[e];
            dst = eidx[e + E];
        }
        es[t] = emb[(size_t)src * 256 + t];
        ed[t] = emb[(size_t)dst * 256 + t];
        __syncthreads();
        float h = b1[t];
#pragma unroll 8
        for (int k = 0; k < 256; ++k) h += es[k] * W1[k * 256 + t];
#pragma unroll 8
        for (int k = 0; k < 256; ++k) h += ed[k] * W1[(256 + k) * 256 + t];
        red[t] = fmaxf(h, 0.f) * W2[t];
        __syncthreads();
        for (int s = 128; s; s >>= 1) {
            if (t < s) red[t] += red[t + s];
            __syncthreads();
        }
        if (t == 0) {
            float z = red[0] + b2[0];
            float sc = 1.0f / (1.0f + expf(-z));
            rescored[c] = ((unsigned long long)__float_as_uint(sc) << 32) |
                          (unsigned)(0xFFFFFFFFu - e);
        }
        __syncthreads();
    }
}

// ---------------------------------------------------------------------------
// K6: top-K via single-block LDS bitonic sort (descending), parallel decode.
// ---------------------------------------------------------------------------
__global__ __launch_bounds__(256) void final_topk(unsigned long long* __restrict__ rescored,
                                                  const unsigned* __restrict__ misc,
                                                  const int* __restrict__ eidx,
                                                  float* __restrict__ out, int E) {
    __shared__ unsigned long long a[SORT_CAP];
    const int t = threadIdx.x;
    const int C = (int)min(misc[3], (unsigned)CAND_CAP);
    const int is64 = (int)misc[0];

    if (C <= SORT_CAP) {
        int n = 256;
        while (n < C) n <<= 1;
        for (int i = t; i < n; i += 256) a[i] = (i < C) ? rescored[i] : 0ull;
        __syncthreads();
        for (int k = 2; k <= n; k <<= 1) {
            for (int j = k >> 1; j > 0; j >>= 1) {
                for (int i = t; i < n; i += 256) {
                    int ixj = i ^ j;
                    if (ixj > i) {
                        unsigned long long x = a[i], y = a[ixj];
                        bool sw = ((i & k) == 0) ? (x < y) : (x > y);
                        if (sw) { a[i] = y; a[ixj] = x; }
                    }
                }
                __syncthreads();
            }
        }
        if (t < TOPK) {
            unsigned long long m = a[t];
            if (m != 0ull) {
                unsigned bits = (unsigned)(m >> 32);
                unsigned e = 0xFFFFFFFFu - (unsigned)(m & 0xFFFFFFFFu);
                int src, dst;
                if (is64) {
                    src = eidx[2 * (size_t)e];
                    dst = eidx[2 * ((size_t)e + E)];
                } else {
                    src = eidx[e];
                    dst = eidx[e + E];
                }
                out[t] = (float)src;
                out[TOPK + t] = (float)dst;
                out[2 * TOPK + t] = __uint_as_float(bits);
            } else {
                out[t] = -1.f;
                out[TOPK + t] = -1.f;
                out[2 * TOPK + t] = -1.f;
            }
        }
        return;
    }

    // fallback: serial removal tournament (pathological only)
    __shared__ unsigned long long red[256];
    for (int r = 0; r < TOPK; ++r) {
        unsigned long long best = 0ull;
        for (int i = t; i < C; i += 256) {
            unsigned long long v = rescored[i];
            if (v > best) best = v;
        }
        red[t] = best;
        __syncthreads();
        for (int s = 128; s; s >>= 1) {
            if (t < s) {
                if (red[t + s] > red[t]) red[t] = red[t + s];
            }
            __syncthreads();
        }
        unsigned long long m = red[0];
        __syncthreads();
        for (int i = t; i < C; i += 256)
            if (rescored[i] == m) rescored[i] = 0ull;
        if (t == 0) {
            if (m != 0ull) {
                unsigned bits = (unsigned)(m >> 32);
                unsigned e = 0xFFFFFFFFu - (unsigned)(m & 0xFFFFFFFFu);
                int src, dst;
                if (is64) {
                    src = eidx[2 * (size_t)e];
                    dst = eidx[2 * ((size_t)e + E)];
                } else {
                    src = eidx[e];
                    dst = eidx[e + E];
                }
                out[r] = (float)src;
                out[TOPK + r] = (float)dst;
                out[2 * TOPK + r] = __uint_as_float(bits);
            } else {
                out[r] = -1.f;
                out[TOPK + r] = -1.f;
                out[2 * TOPK + r] = -1.f;
            }
        }
        __syncthreads();
    }
}

// ---------------------------------------------------------------------------
extern "C" void kernel_launch(void* const* d_in, const int* in_sizes, int n_in,
                              void* d_out, int out_size, void* d_ws, size_t ws_size,
                              hipStream_t stream) {
    const float* emb = (const float*)d_in[0];
    const float* W1  = (const float*)d_in[1];
    const float* b1  = (const float*)d_in[2];
    const float* W2  = (const float*)d_in[3];
    const float* b2  = (const float*)d_in[4];
    const int*   eidx = (const int*)d_in[5];

    const int M = in_sizes[0] / 256;           // 50000
    const int E = in_sizes[5] / 2;             // 800000
    const int Mpad = ((M + 63) / 64) * 64;     // 50048
    const int NG = Mpad / 64;                  // gemm blocks (782)

    char* p = (char*)d_ws;
    auto alloc = [&](size_t bytes) {
        char* r = p;
        p += (bytes + 255) & ~(size_t)255;
        return r;
    };
    unsigned* Wcf4 = (unsigned*)alloc(256 * 512 * 2);              // bf16 B-frags
    unsigned char* C8 = (unsigned char*)alloc((size_t)Mpad * 512); // fp8 C
    float* svals = (float*)alloc((size_t)E * 4);
    int* vsrc = (int*)alloc((size_t)E * 4);
    int* vdst = (int*)alloc((size_t)E * 4);
    int* vid  = (int*)alloc((size_t)E * 4);
    unsigned* hist = (unsigned*)alloc(HIST_BINS * 4);
    unsigned long long* cand = (unsigned long long*)alloc(CAND_CAP * 8);
    unsigned long long* resc = (unsigned long long*)alloc(CAND_CAP * 8);
    unsigned* bcount = (unsigned*)alloc(NFBLK * 4);
    unsigned* misc = (unsigned*)alloc(256);

    float* out = (float*)d_out;

    prep_count<<<NFBLK, 256, 0, stream>>>(W1, Wcf4, hist, misc, eidx, bcount, E);

    gemm_plus_write<<<NG + NFBLK, 256, 0, stream>>>(emb, (const bf16x8*)Wcf4, b1, C8,
                                                    M, NG, eidx, misc, bcount,
                                                    vsrc, vdst, vid, E);

    edge_score_fp8<<<2048, 256, 0, stream>>>(C8, vsrc, vdst, W2, b2, svals, misc);

    hist_kernel<<<128, 256, 0, stream>>>(svals, misc, hist);

    compact<<<512, 256, 0, stream>>>(svals, vid, hist, misc, cand);

    rescore<<<1024, 256, 0, stream>>>(emb, W1, b1, W2, b2, eidx, cand, misc, resc, E);

    final_topk<<<1, 256, 0, stream>>>(resc, misc, eidx, out, E);
}